// Round 2
// baseline (983.457 us; speedup 1.0000x reference)
//
#include <hip/hip_runtime.h>
#include <cstddef>
#include <cstdint>

// Problem constants (match reference setup_inputs()).
#define N_NODES 100000
#define N_EDGES 640000
#define EMBD    128
#define NBATCH  16384

// ---------------------------------------------------------------------------
// Scatter: A[r][dst] += ew[e] * x[src]  (one wave per edge, 2 dims/lane)
// Exploits linearity: (sum_e w_e x_src) @ W_r == sum_e w_e (x_src @ W_r),
// turning 640k per-edge 128x128 matvecs into a scatter + one dense GEMM.
// ---------------------------------------------------------------------------
__global__ __launch_bounds__(256) void scatter_kernel(
    const float* __restrict__ x, const int* __restrict__ ei,
    const int* __restrict__ et, const float* __restrict__ ew,
    float* __restrict__ A, int E, int N)
{
    const int lane = threadIdx.x & 63;
    const int wid  = blockIdx.x * (blockDim.x >> 6) + (threadIdx.x >> 6);
    const int nw   = gridDim.x * (blockDim.x >> 6);
    for (int e = wid; e < E; e += nw) {
        const int   src = ei[e];
        const int   dst = ei[E + e];
        const int   r   = et[e];
        const float w   = ew[e];
        const float* xr = x + (size_t)src * EMBD;
        const float v0 = xr[lane]      * w;
        const float v1 = xr[lane + 64] * w;
        float* ar = A + ((size_t)r * N + dst) * EMBD;
        atomicAdd(ar + lane,      v0);
        atomicAdd(ar + lane + 64, v1);
    }
}

// ---------------------------------------------------------------------------
// Fused GEMM: out[M,128] = S0@W0 + S1@W1 + S2@W2 + bias, optional ReLU+LN.
// Virtual K=384 (three 128-wide sources). BM=64, BN=128 (full), BK=32.
// 256 threads: thread (ty=t>>5, tx=t&31) owns rows ty*8..+7, cols tx*4..+3.
// NOTE: each block reads only rows [m0, m0+64) of S0/S1/S2 and writes the
// same rows of `out` after a barrier — so `out` may safely alias S0/S1/S2.
// ---------------------------------------------------------------------------
__global__ __launch_bounds__(256) void gemm_fused(
    const float* __restrict__ S0, const float* __restrict__ S1, const float* __restrict__ S2,
    const float* __restrict__ W0, const float* __restrict__ W1, const float* __restrict__ W2,
    const float* __restrict__ bias, const float* __restrict__ lng, const float* __restrict__ lnb,
    float* __restrict__ out, int M, int do_ln)
{
    __shared__ float As[32][68];    // [k][row], +4 pad keeps float4 alignment, breaks stride-64
    __shared__ float Bs[32][128];   // [k][col]

    const int t  = threadIdx.x;
    const int tx = t & 31, ty = t >> 5;
    const int m0 = blockIdx.x * 64;

    float acc[8][4];
#pragma unroll
    for (int j = 0; j < 8; ++j)
#pragma unroll
        for (int i = 0; i < 4; ++i) acc[j][i] = 0.f;

    const float* Ss[3] = {S0, S1, S2};
    const float* Ws[3] = {W0, W1, W2};

    const int arow = t >> 3;        // 0..31 (two passes of 32 rows)
    const int akk  = (t & 7) * 4;   // k-slot within 32
    const int brow = t >> 5;        // 0..7 (four passes of 8 rows)
    const int bcol = (t & 31) * 4;

    for (int kc = 0; kc < 12; ++kc) {
        const float* S = Ss[kc >> 2];
        const float* W = Ws[kc >> 2];
        const int koff = (kc & 3) * 32;

#pragma unroll
        for (int p = 0; p < 2; ++p) {           // A tile 64x32, stored transposed
            const int row = arow + p * 32;
            const int rg  = m0 + row;
            float4 f;
            if (rg < M) f = *(const float4*)(S + (size_t)rg * EMBD + koff + akk);
            else        f = make_float4(0.f, 0.f, 0.f, 0.f);
            As[akk + 0][row] = f.x;
            As[akk + 1][row] = f.y;
            As[akk + 2][row] = f.z;
            As[akk + 3][row] = f.w;
        }
#pragma unroll
        for (int p = 0; p < 4; ++p) {           // B tile 32x128
            const int row = brow + p * 8;
            float4 f = *(const float4*)(W + (size_t)(koff + row) * EMBD + bcol);
            *(float4*)&Bs[row][bcol] = f;
        }
        __syncthreads();

#pragma unroll
        for (int k = 0; k < 32; ++k) {
            const float4 a0 = *(const float4*)&As[k][ty * 8];
            const float4 a1 = *(const float4*)&As[k][ty * 8 + 4];
            const float4 b  = *(const float4*)&Bs[k][tx * 4];
            const float av[8] = {a0.x, a0.y, a0.z, a0.w, a1.x, a1.y, a1.z, a1.w};
            const float bv[4] = {b.x, b.y, b.z, b.w};
#pragma unroll
            for (int j = 0; j < 8; ++j)
#pragma unroll
                for (int i = 0; i < 4; ++i) acc[j][i] += av[j] * bv[i];
        }
        __syncthreads();
    }

    // Epilogue
    const float4 bias4 = *(const float4*)(bias + tx * 4);
    const float bb[4] = {bias4.x, bias4.y, bias4.z, bias4.w};
    float gg[4] = {0.f, 0.f, 0.f, 0.f}, bt[4] = {0.f, 0.f, 0.f, 0.f};
    if (do_ln) {
        const float4 g4 = *(const float4*)(lng + tx * 4);
        const float4 b4 = *(const float4*)(lnb + tx * 4);
        gg[0] = g4.x; gg[1] = g4.y; gg[2] = g4.z; gg[3] = g4.w;
        bt[0] = b4.x; bt[1] = b4.y; bt[2] = b4.z; bt[3] = b4.w;
    }
#pragma unroll
    for (int j = 0; j < 8; ++j) {
        const int rg = m0 + ty * 8 + j;
        float v[4];
#pragma unroll
        for (int i = 0; i < 4; ++i) v[i] = acc[j][i] + bb[i];
        if (do_ln) {
#pragma unroll
            for (int i = 0; i < 4; ++i) v[i] = fmaxf(v[i], 0.f);
            // LayerNorm over 128 cols: row lives in one 32-lane half-wave.
            float s  = v[0] + v[1] + v[2] + v[3];
            float sq = v[0]*v[0] + v[1]*v[1] + v[2]*v[2] + v[3]*v[3];
#pragma unroll
            for (int off = 16; off > 0; off >>= 1) {
                s  += __shfl_xor(s,  off, 32);
                sq += __shfl_xor(sq, off, 32);
            }
            const float mu   = s * (1.0f / 128.0f);
            const float var  = sq * (1.0f / 128.0f) - mu * mu;
            const float rstd = rsqrtf(var + 1e-5f);
#pragma unroll
            for (int i = 0; i < 4; ++i) v[i] = (v[i] - mu) * rstd * gg[i] + bt[i];
        }
        if (rg < M) {
            *(float4*)(out + (size_t)rg * EMBD + tx * 4) = make_float4(v[0], v[1], v[2], v[3]);
        }
    }
}

// ---------------------------------------------------------------------------
// Fused head: gather u/v, l2 norms, GMF, MLP 256->128->64->32, out proj,
// sigmoid. 16 batch rows per 256-thread block, everything staged in LDS.
// ---------------------------------------------------------------------------
__global__ __launch_bounds__(256) void head_kernel(
    const float* __restrict__ x2, const int* __restrict__ ui, const int* __restrict__ vi,
    const float* __restrict__ mw0, const float* __restrict__ mb0,
    const float* __restrict__ mw1, const float* __restrict__ mb1,
    const float* __restrict__ mw2, const float* __restrict__ mb2,
    const float* __restrict__ ow, const float* __restrict__ ob,
    float* __restrict__ out, int B)
{
    __shared__ float h0[16][256];   // concat(u, v)
    __shared__ float h1[16][128];
    __shared__ float h2[16][64];
    __shared__ float h3[16][32];
    __shared__ float ps_u[16][16], ps_v[16][16];
    __shared__ float inv_nunv[16];
    __shared__ float pg[16][16], ph[16][16];

    const int t   = threadIdx.x;
    const int bb0 = blockIdx.x * 16;

    // Gather u,v
    for (int r = 0; r < 16; ++r) {
        const int b   = bb0 + r;
        const int idx = (t < 128) ? ui[b] : vi[b];
        const int c   = t & 127;
        h0[r][t] = x2[(size_t)idx * EMBD + c];
    }
    __syncthreads();

    // L2-norm partials (16 threads per row)
    {
        const int row = t >> 4, sub = t & 15;
        float su = 0.f, sv = 0.f;
#pragma unroll
        for (int k = 0; k < 8; ++k) {
            const float a = h0[row][sub + 16 * k];       su += a * a;
            const float b = h0[row][128 + sub + 16 * k]; sv += b * b;
        }
        ps_u[row][sub] = su; ps_v[row][sub] = sv;
    }
    __syncthreads();
    if (t < 16) {
        float su = 0.f, sv = 0.f;
#pragma unroll
        for (int k = 0; k < 16; ++k) { su += ps_u[t][k]; sv += ps_v[t][k]; }
        const float nu = fmaxf(sqrtf(su), 1e-12f);
        const float nv = fmaxf(sqrtf(sv), 1e-12f);
        inv_nunv[t] = 1.0f / (nu * nv);
    }
    __syncthreads();

    // MLP layer 0: [16,256] @ [256,128] -> relu
    {
        const int c = t & 127, rr = t >> 7;   // rr in {0,1}: rows rr*8..+7
        float acc[8];
#pragma unroll
        for (int j = 0; j < 8; ++j) acc[j] = 0.f;
        for (int i = 0; i < 256; i += 4) {
            const float w0 = mw0[(i + 0) * 128 + c];
            const float w1 = mw0[(i + 1) * 128 + c];
            const float w2 = mw0[(i + 2) * 128 + c];
            const float w3 = mw0[(i + 3) * 128 + c];
#pragma unroll
            for (int j = 0; j < 8; ++j) {
                const float4 a = *(const float4*)&h0[rr * 8 + j][i];
                acc[j] += a.x * w0 + a.y * w1 + a.z * w2 + a.w * w3;
            }
        }
        const float bv = mb0[c];
#pragma unroll
        for (int j = 0; j < 8; ++j) h1[rr * 8 + j][c] = fmaxf(acc[j] + bv, 0.f);
    }
    __syncthreads();

    // MLP layer 1: [16,128] @ [128,64] -> relu
    {
        const int c = t & 63, g = t >> 6;     // g in 0..3: rows g*4..+3
        float acc[4] = {0.f, 0.f, 0.f, 0.f};
        for (int i = 0; i < 128; i += 4) {
            const float w0 = mw1[(i + 0) * 64 + c];
            const float w1 = mw1[(i + 1) * 64 + c];
            const float w2 = mw1[(i + 2) * 64 + c];
            const float w3 = mw1[(i + 3) * 64 + c];
#pragma unroll
            for (int j = 0; j < 4; ++j) {
                const float4 a = *(const float4*)&h1[g * 4 + j][i];
                acc[j] += a.x * w0 + a.y * w1 + a.z * w2 + a.w * w3;
            }
        }
        const float bv = mb1[c];
#pragma unroll
        for (int j = 0; j < 4; ++j) h2[g * 4 + j][c] = fmaxf(acc[j] + bv, 0.f);
    }
    __syncthreads();

    // MLP layer 2: [16,64] @ [64,32] -> relu
    {
        const int c = t & 31, g = t >> 5;     // g in 0..7: rows g*2..+1
        float acc[2] = {0.f, 0.f};
        for (int i = 0; i < 64; i += 4) {
            const float w0 = mw2[(i + 0) * 32 + c];
            const float w1 = mw2[(i + 1) * 32 + c];
            const float w2 = mw2[(i + 2) * 32 + c];
            const float w3 = mw2[(i + 3) * 32 + c];
#pragma unroll
            for (int j = 0; j < 2; ++j) {
                const float4 a = *(const float4*)&h2[g * 2 + j][i];
                acc[j] += a.x * w0 + a.y * w1 + a.z * w2 + a.w * w3;
            }
        }
        const float bv = mb2[c];
#pragma unroll
        for (int j = 0; j < 2; ++j) h3[g * 2 + j][c] = fmaxf(acc[j] + bv, 0.f);
    }
    __syncthreads();

    // Output: sigmoid( [gmf(128) | h3(32)] @ ow + ob )
    {
        const int row = t >> 4, sub = t & 15;
        float pgv = 0.f;
#pragma unroll
        for (int k = 0; k < 8; ++k) {
            const int c = sub + 16 * k;
            pgv += h0[row][c] * h0[row][128 + c] * ow[c];   // u*v (un-normalized)
        }
        const float phv = h3[row][sub]      * ow[128 + sub]
                        + h3[row][sub + 16] * ow[144 + sub];
        pg[row][sub] = pgv; ph[row][sub] = phv;
    }
    __syncthreads();
    if (t < 16) {
        float sg = 0.f, sh = 0.f;
#pragma unroll
        for (int k = 0; k < 16; ++k) { sg += pg[t][k]; sh += ph[t][k]; }
        const float z = sg * inv_nunv[t] + sh + ob[0];
        out[bb0 + t] = 1.0f / (1.0f + expf(-z));
    }
}

// ---------------------------------------------------------------------------
// Launch. ws layout (153.6 MB total):
//   A[2][N][128]  (102.4 MB)   — per-relation scatter accumulators
//   x1[N][128]    ( 51.2 MB)   — layer-1 output
//   x2 ALIASES A[0]            — safe: gemm_fused writes its own row range
//                                only after reading it (see kernel note)
// ---------------------------------------------------------------------------
extern "C" void kernel_launch(void* const* d_in, const int* in_sizes, int n_in,
                              void* d_out, int out_size, void* d_ws, size_t ws_size,
                              hipStream_t stream)
{
    const int*   ui      = (const int*)d_in[0];
    const int*   vi      = (const int*)d_in[1];
    const int*   ei      = (const int*)d_in[2];
    const int*   et      = (const int*)d_in[3];
    const float* ew      = (const float*)d_in[4];
    const float* emb     = (const float*)d_in[5];
    const float* w1_rel  = (const float*)d_in[6];
    const float* w1_root = (const float*)d_in[7];
    const float* b1      = (const float*)d_in[8];
    const float* ln_g    = (const float*)d_in[9];
    const float* ln_b    = (const float*)d_in[10];
    const float* w2_rel  = (const float*)d_in[11];
    const float* w2_root = (const float*)d_in[12];
    const float* b2      = (const float*)d_in[13];
    const float* mw0     = (const float*)d_in[14];
    const float* mb0     = (const float*)d_in[15];
    const float* mw1     = (const float*)d_in[16];
    const float* mb1     = (const float*)d_in[17];
    const float* mw2     = (const float*)d_in[18];
    const float* mb2     = (const float*)d_in[19];
    const float* ow      = (const float*)d_in[20];
    const float* ob      = (const float*)d_in[21];
    float* out = (float*)d_out;

    const int N = N_NODES, E = N_EDGES, B = NBATCH;

    float* A  = (float*)d_ws;                      // [2][N][128]
    float* x1 = A  + (size_t)2 * N * EMBD;         // [N][128]
    float* x2 = A;                                 // aliases A[0] (see note)

    const size_t abytes = (size_t)2 * N * EMBD * sizeof(float);

    // ---- Layer 1: agg_r = scatter(w_e * emb[src]); x1 = LN(relu(GEMM)) ----
    hipMemsetAsync(A, 0, abytes, stream);
    scatter_kernel<<<4096, 256, 0, stream>>>(emb, ei, et, ew, A, E, N);
    gemm_fused<<<(N + 63) / 64, 256, 0, stream>>>(
        A, A + (size_t)N * EMBD, emb,
        w1_rel, w1_rel + 128 * 128, w1_root,
        b1, ln_g, ln_b, x1, N, 1);

    // ---- Layer 2: agg_r = scatter(w_e * x1[src]); x2 = GEMM + bias ----
    hipMemsetAsync(A, 0, abytes, stream);
    scatter_kernel<<<4096, 256, 0, stream>>>(x1, ei, et, ew, A, E, N);
    gemm_fused<<<(N + 63) / 64, 256, 0, stream>>>(
        A, A + (size_t)N * EMBD, x1,
        w2_rel, w2_rel + 128 * 128, w2_root,
        b2, nullptr, nullptr, x2, N, 0);

    // ---- Head: gather + GMF + MLP + output ----
    head_kernel<<<B / 16, 256, 0, stream>>>(
        x2, ui, vi, mw0, mb0, mw1, mb1, mw2, mb2, ow, ob, out, B);
}